// Round 22
// baseline (279.495 us; speedup 1.0000x reference)
//
#include <hip/hip_runtime.h>
#include <hip/hip_bf16.h>

#define TOTAL_N   131072
#define NEDGE     4194304
#define NPG       2048
#define IN_DIM_K  128
#define HID_K     256
#define EMB_K     64
#define NAGENT    64

#define F1CAP     4096
#define APACK     128        // per-agent e0 slot cap
#define BCAP      96         // per-F1-node edge bucket cap (mean 32, P(>96)~1e-18)

#define G1        256                 // k_outdeg_e0 blocks
#define EPB1      (NEDGE / G1)        // 16384 edges per block
#define HWORDS    (TOTAL_N / 8)       // 16384 nibble-packed u32 words

#define SELB      256                 // k_e1_select blocks (persistent)
#define EPB       (NEDGE / SELB)      // 16384 edges per block

// ---------------- workspace layout (bytes) ----------------
// zeroed every launch [0, 34048):
//   0        counters  int[256]        ([1]=nF1)
//   1024     inF1      int[F1CAP]      16K
//   17408    e0cnt     int[64]         256B
//   17664    bitmap    u32[4096]       16K
// not zeroed (fully written before read):
//   65536    loc       int[TOTAL_N]    512K
//   589824   e0pack    int[64*APACK]   32K
//   622592   es_bucket int[F1CAP*BCAP] 1.5M
//   2195456  out_deg   u32[TOTAL_N]    512K
//   2719744  wswz      u16[32768]      64K
//   2785280  h1        f32[F1CAP*HID]  4M
//   6979584  agg1      f32[F1CAP*HID]  4M
//   11173888 partial   u32[G1*HWORDS]  16M
// total ~26.7 MB

#define ZERO_SPAN 34048

typedef float f32x4 __attribute__((ext_vector_type(4)));
typedef short bf16x8 __attribute__((ext_vector_type(8)));

__device__ inline unsigned short f2bf(float f) {   // RNE f32->bf16
    unsigned int u = __float_as_uint(f);
    return (unsigned short)((u + 0x7FFFu + ((u >> 16) & 1u)) >> 16);
}

// K1: out-degree nibble histogram + e0 select + F1 bitmap marking (r17-proven)
__global__ __launch_bounds__(1024) void k_outdeg_e0(
    const int* __restrict__ src, const int* __restrict__ dst,
    unsigned int* __restrict__ partial,
    unsigned int* __restrict__ bitmap,
    int* __restrict__ e0pack, int* __restrict__ e0cnt)
{
    __shared__ unsigned int hist[HWORDS];   // 64 KB
    int t = threadIdx.x;
    #pragma unroll
    for (int i = 0; i < HWORDS / 1024; i++) hist[t + i * 1024] = 0u;
    __syncthreads();

    int ebase = blockIdx.x * EPB1;
    const int4* s4 = (const int4*)(src + ebase);
    const int4* d4 = (const int4*)(dst + ebase);
    #pragma unroll
    for (int i = 0; i < EPB1 / 4096; i++) {     // 4 iterations
        int4 sv = s4[i * 1024 + t];
        int4 dv = d4[i * 1024 + t];
        int ss[4] = {sv.x, sv.y, sv.z, sv.w};
        int dd[4] = {dv.x, dv.y, dv.z, dv.w};
        #pragma unroll
        for (int j = 0; j < 4; j++) {
            int s = ss[j], d = dd[j];
            atomicAdd(&hist[s >> 3], 1u << ((s & 7) * 4));
            if ((d & (NPG - 1)) == 0) {
                atomicOr(&bitmap[s >> 5], 1u << (s & 31));
                int a = d >> 11;
                int slot = atomicAdd(&e0cnt[a], 1);
                if (slot < APACK) e0pack[a * APACK + slot] = s;
            }
        }
    }
    __syncthreads();
    unsigned int* pout = partial + blockIdx.x * HWORDS;
    #pragma unroll
    for (int i = 0; i < HWORDS / 1024; i++) pout[t + i * 1024] = hist[t + i * 1024];
}

// K2 (merged aux+reduce, 260 blocks x 1024):
//   [0,128) compact | [128,256) out_deg reduce | [256,260) wprep
__global__ __launch_bounds__(1024) void k_auxred(
    const unsigned int* __restrict__ bitmap, int* __restrict__ loc,
    int* __restrict__ counters,
    const unsigned int* __restrict__ partial, unsigned int* __restrict__ out_deg,
    const float* __restrict__ wlin, unsigned short* __restrict__ wswz)
{
    int b = blockIdx.x;
    int t = threadIdx.x;
    if (b < 128) {
        __shared__ int cnt, gbase;
        if (t == 0) cnt = 0;
        __syncthreads();
        int v = b * 1024 + t;
        int f = (bitmap[v >> 5] >> (v & 31)) & 1u;
        int p = -1;
        if (f) p = atomicAdd(&cnt, 1);
        __syncthreads();
        if (t == 0) gbase = cnt ? atomicAdd(&counters[1], cnt) : 0;
        __syncthreads();
        int l = -1;
        if (p >= 0) { int id = gbase + p; if (id < F1CAP) l = id; }
        loc[v] = l;
    } else if (b < 256) {
        __shared__ unsigned int redE[8][128], redO[8][128];   // 8 KB
        int wl = t & 127, gs = t >> 7;
        int w = (b - 128) * 128 + wl;
        unsigned int accE = 0, accO = 0;
        #pragma unroll 8
        for (int i = 0; i < 32; i++) {
            unsigned int v = partial[(gs * 32 + i) * HWORDS + w];
            accE += v & 0x0F0F0F0Fu;
            accO += (v >> 4) & 0x0F0F0F0Fu;
        }
        redE[gs][wl] = accE;
        redO[gs][wl] = accO;
        __syncthreads();
        if (gs == 0) {
            unsigned int sE = 0, sO = 0;
            #pragma unroll
            for (int j = 0; j < 8; j++) { sE += redE[j][wl]; sO += redO[j][wl]; }
            uint4 lo = make_uint4(sE & 255u, sO & 255u, (sE >> 8) & 255u, (sO >> 8) & 255u);
            uint4 hi = make_uint4((sE >> 16) & 255u, (sO >> 16) & 255u, (sE >> 24) & 255u, (sO >> 24) & 255u);
            ((uint4*)(out_deg + 8 * w))[0] = lo;
            ((uint4*)(out_deg + 8 * w))[1] = hi;
        }
    } else {
        int g = (b - 256) * 1024 + t;            // 4096 items
        int lane = g & 63, ct = (g >> 6) & 15, kt = g >> 10;
        int colbase = ct * 16 + (lane & 15);
        int kbase = kt * 32 + (lane >> 4) * 8;
        unsigned short o[8];
        #pragma unroll
        for (int i = 0; i < 8; i++) o[i] = f2bf(wlin[(kbase + i) * HID_K + colbase]);
        *(ushort4*)(wswz + g * 8)     = make_ushort4(o[0], o[1], o[2], o[3]);
        *(ushort4*)(wswz + g * 8 + 4) = make_ushort4(o[4], o[5], o[6], o[7]);
    }
}

// K3: select edges with dst in F1 — direct bucket scatter; slot atomic doubles
// as the inF1 in-degree count.
__global__ __launch_bounds__(1024) void k_e1_select(
    const int* __restrict__ src, const int* __restrict__ dst,
    const int* __restrict__ loc, const unsigned int* __restrict__ bitmap,
    int* __restrict__ inF1, int* __restrict__ es_bucket)
{
    __shared__ unsigned int bm[TOTAL_N / 32];   // 16 KB
    int t = threadIdx.x;
    ((uint4*)bm)[t] = ((const uint4*)bitmap)[t];
    __syncthreads();

    int ebase = blockIdx.x * EPB;
    const int4* d4p = (const int4*)(dst + ebase);
    #pragma unroll
    for (int i = 0; i < EPB / 4096; i++) {      // 4 iterations
        int4 d4 = d4p[i * 1024 + t];
        int eidx = ebase + (i * 1024 + t) * 4;
        int dd[4] = {d4.x, d4.y, d4.z, d4.w};
        #pragma unroll
        for (int j = 0; j < 4; j++) {
            int d = dd[j];
            if ((bm[d >> 5] >> (d & 31)) & 1u) {
                int l = loc[d];
                if (l >= 0) {
                    int slot = atomicAdd(&inF1[l], 1);
                    if (slot < BCAP) es_bucket[l * BCAP + slot] = src[eidx + j];
                }
            }
        }
    }
}

// K4 (wave-per-node, LDS-staged COALESCED gather, VGPR-capped):
// 4 nodes per 256-thread block, one per 64-lane wave. No barriers (wave-
// private LDS slices; r19-proven pattern). Gather is coalesced: lanes read
// consecutive float4s WITHIN rows (no fragment-amplification — the r21
// lesson). __launch_bounds__(256,4) caps VGPR at 128 (the r19 lesson);
// gather unrolled only 4x to keep register pressure down.
__global__ __launch_bounds__(256, 4) void k_h0agg(
    const float* __restrict__ x, const unsigned short* __restrict__ wswz,
    const float* __restrict__ blin, const int* __restrict__ es_bucket,
    const unsigned int* __restrict__ out_deg, const int* __restrict__ inF1,
    const int* __restrict__ counters, float* __restrict__ agg1)
{
    __shared__ unsigned short A[4][32][136];   // 34 KB (4 wave-private tiles)
    __shared__ float escs[4][32];
    __shared__ int rsrc[4][32];

    int nF1 = min(counters[1], F1CAP);
    int t = threadIdx.x;
    int w = t >> 6, lane = t & 63;
    int l = blockIdx.x * 4 + w;
    if (l >= nF1) return;                      // per-wave exit (no barriers)
    int cnt = min(inF1[l], BCAP);
    int ntile = (cnt + 31) >> 5;
    int cbase = lane & 15, rgrp = (lane >> 4) * 4;

    float colacc[16];
    #pragma unroll
    for (int n = 0; n < 16; n++) colacc[n] = 0.f;

    for (int ti = 0; ti < ntile; ti++) {
        if (lane < 32) {
            int r = ti * 32 + lane;
            int s = (r < cnt) ? es_bucket[l * BCAP + r] : -1;
            rsrc[w][lane] = s;
            escs[w][lane] = (s >= 0) ? rsqrtf((float)max((int)out_deg[s], 1)) : 0.f;
        }
        // coalesced gather: 1024 float4 slots over 64 lanes, rows contiguous
        #pragma unroll 4
        for (int i = 0; i < 16; i++) {
            int idx = lane + i * 64;
            int r2 = idx >> 5, q = idx & 31;
            int s2 = rsrc[w][r2];
            float4 v = make_float4(0.f, 0.f, 0.f, 0.f);
            if (s2 >= 0) v = ((const float4*)(x + (long long)s2 * IN_DIM_K))[q];
            ushort4 h;
            h.x = f2bf(v.x); h.y = f2bf(v.y); h.z = f2bf(v.z); h.w = f2bf(v.w);
            *(ushort4*)&A[w][r2][q * 4] = h;
        }
        // A-fragments for both m-tiles (rows 0-15, 16-31)
        bf16x8 a0[4], a1[4];
        const unsigned short* Ab = &A[w][0][0];
        #pragma unroll
        for (int kt = 0; kt < 4; kt++) {
            a0[kt] = *(const bf16x8*)(Ab + ((lane & 15) * 136 + kt * 32 + (lane >> 4) * 8));
            a1[kt] = *(const bf16x8*)(Ab + (((lane & 15) + 16) * 136 + kt * 32 + (lane >> 4) * 8));
        }
        #pragma unroll
        for (int n = 0; n < 16; n++) {
            f32x4 acc0 = (f32x4){0.f, 0.f, 0.f, 0.f};
            f32x4 acc1 = (f32x4){0.f, 0.f, 0.f, 0.f};
            #pragma unroll
            for (int kt = 0; kt < 4; kt++) {
                bf16x8 bf = *(const bf16x8*)(wswz + ((kt * 16 + n) * 64 + lane) * 8);
                acc0 = __builtin_amdgcn_mfma_f32_16x16x32_bf16(a0[kt], bf, acc0, 0, 0, 0);
                acc1 = __builtin_amdgcn_mfma_f32_16x16x32_bf16(a1[kt], bf, acc1, 0, 0, 0);
            }
            float bj = blin[n * 16 + cbase];
            float part = 0.f;
            #pragma unroll
            for (int j = 0; j < 4; j++) {
                part += fmaxf(acc0[j] + bj, 0.f) * escs[w][rgrp + j];
                part += fmaxf(acc1[j] + bj, 0.f) * escs[w][16 + rgrp + j];
            }
            part += __shfl_xor(part, 16);
            part += __shfl_xor(part, 32);
            colacc[n] += part;
        }
    }

    if (lane < 16) {
        #pragma unroll
        for (int n = 0; n < 16; n++)
            agg1[(long long)l * HID_K + n * 16 + lane] = colacc[n];
    }
}

// K5: h1 = relu((agg1*in_norm)@wc0 + bc0), column-split 4x (r18-proven)
__global__ __launch_bounds__(256) void k_h1(
    const float* __restrict__ agg1, const float* __restrict__ wc0,
    const float* __restrict__ bc0,
    const int* __restrict__ inF1,
    const int* __restrict__ counters, float* __restrict__ h1)
{
    __shared__ float as[16][HID_K];   // 16 KB
    __shared__ float ns[16];

    int nF1 = min(counters[1], F1CAP);
    int rt = blockIdx.x >> 2;
    int cq = blockIdx.x & 3;
    int base = rt * 16;
    if (base >= nF1) return;
    int t = threadIdx.x;

    if (t < 16) {
        int l = base + t;
        ns[t] = (l < nF1) ? rsqrtf((float)max(inF1[l], 1)) : 0.f;
    }
    __syncthreads();

    #pragma unroll
    for (int i = 0; i < 4; i++) {
        int idx = t + i * 256;
        int e = idx >> 6;
        int q = idx & 63;
        int l = base + e;
        float4 v = make_float4(0.f, 0.f, 0.f, 0.f);
        if (l < nF1) v = ((const float4*)(agg1 + (long long)l * HID_K))[q];
        float sc = ns[e];
        v.x *= sc; v.y *= sc; v.z *= sc; v.w *= sc;
        ((float4*)as[e])[q] = v;
    }
    __syncthreads();

    int j = cq * 64 + (t & 63);
    int rg = (t >> 6) * 4;
    float acc[4] = {0.f, 0.f, 0.f, 0.f};

    for (int k = 0; k < HID_K; k += 4) {
        float w0 = wc0[(k + 0) * HID_K + j];
        float w1 = wc0[(k + 1) * HID_K + j];
        float w2 = wc0[(k + 2) * HID_K + j];
        float w3 = wc0[(k + 3) * HID_K + j];
        #pragma unroll
        for (int e = 0; e < 4; e++) {
            float4 av = *(const float4*)&as[rg + e][k];
            acc[e] = fmaf(av.x, w0, acc[e]);
            acc[e] = fmaf(av.y, w1, acc[e]);
            acc[e] = fmaf(av.z, w2, acc[e]);
            acc[e] = fmaf(av.w, w3, acc[e]);
        }
    }

    float bj = bc0[j];
    #pragma unroll
    for (int e = 0; e < 4; e++) {
        int l = base + rg + e;
        if (l < nF1) h1[(long long)l * HID_K + j] = fmaxf(acc[e] + bj, 0.f);
    }
}

// K6 (widened, r19-proven): per agent, 1024 threads; phase-sliced GEMVs.
__global__ __launch_bounds__(1024) void k_final(
    const int* __restrict__ e0pack, const int* __restrict__ e0cnt,
    const int* __restrict__ loc, const unsigned int* __restrict__ out_deg,
    const float* __restrict__ h1,
    const float* __restrict__ wc1, const float* __restrict__ bc1,
    const float* __restrict__ wemb, const float* __restrict__ bemb,
    float* __restrict__ out)
{
    __shared__ float part4[4][HID_K];
    __shared__ float a_s[HID_K];
    __shared__ float h2[HID_K];
    __shared__ float o_part[16][EMB_K];
    __shared__ int   ls[APACK];
    __shared__ float scs[APACK];
    int a = blockIdx.x;
    int t = threadIdx.x;

    int n0 = e0cnt[a];
    int ne = min(n0, APACK);
    if (t < ne) {
        int s = e0pack[a * APACK + t];
        int l = loc[s];
        ls[t] = l;
        scs[t] = (l >= 0) ? rsqrtf((float)max((int)out_deg[s], 1)) : 0.f;
    }
    __syncthreads();

    {
        int col = t & 255, sl = t >> 8;
        float acc = 0.f;
        for (int i = sl; i < ne; i += 4) {
            int l = ls[i];
            if (l >= 0) acc = fmaf(scs[i], h1[(long long)l * HID_K + col], acc);
        }
        part4[sl][col] = acc;
    }
    __syncthreads();
    if (t < HID_K) {
        float s = part4[0][t] + part4[1][t] + part4[2][t] + part4[3][t];
        a_s[t] = s * rsqrtf((float)max(n0, 1));
    }
    __syncthreads();

    {
        int col = t & 255, sl = t >> 8;
        float acc = 0.f;
        int k0 = sl * 64;
        for (int k = k0; k < k0 + 64; k++)
            acc = fmaf(a_s[k], wc1[k * HID_K + col], acc);
        part4[sl][col] = acc;
    }
    __syncthreads();
    if (t < HID_K) {
        float s = part4[0][t] + part4[1][t] + part4[2][t] + part4[3][t];
        h2[t] = fmaxf(s + bc1[t], 0.f);
    }
    __syncthreads();

    {
        int col = t & 63, sl = t >> 6;
        float acc = 0.f;
        int k0 = sl * 16;
        for (int k = k0; k < k0 + 16; k++)
            acc = fmaf(h2[k], wemb[k * EMB_K + col], acc);
        o_part[sl][col] = acc;
    }
    __syncthreads();
    if (t < EMB_K) {
        float o = bemb[t];
        #pragma unroll
        for (int s = 0; s < 16; s++) o += o_part[s][t];
        out[a * EMB_K + t] = o;
    }
}

extern "C" void kernel_launch(void* const* d_in, const int* in_sizes, int n_in,
                              void* d_out, int out_size, void* d_ws, size_t ws_size,
                              hipStream_t stream)
{
    const float* x    = (const float*)d_in[0];
    const int*   src  = (const int*)d_in[1];
    const int*   dst  = (const int*)d_in[2];
    const float* wlin = (const float*)d_in[5];
    const float* blin = (const float*)d_in[6];
    const float* wc0  = (const float*)d_in[7];
    const float* bc0  = (const float*)d_in[8];
    const float* wc1  = (const float*)d_in[9];
    const float* bc1  = (const float*)d_in[10];
    const float* wemb = (const float*)d_in[11];
    const float* bemb = (const float*)d_in[12];
    float* out = (float*)d_out;

    char* ws = (char*)d_ws;
    int*            counters  = (int*)(ws + 0);
    int*            inF1      = (int*)(ws + 1024);
    int*            e0cnt     = (int*)(ws + 17408);
    unsigned int*   bitmap    = (unsigned int*)(ws + 17664);
    int*            loc       = (int*)(ws + 65536);
    int*            e0pack    = (int*)(ws + 589824);
    int*            es_bucket = (int*)(ws + 622592);
    unsigned int*   out_deg   = (unsigned int*)(ws + 2195456);
    unsigned short* wswz      = (unsigned short*)(ws + 2719744);
    float*          h1        = (float*)(ws + 2785280);
    float*          agg1      = (float*)(ws + 6979584);
    unsigned int*   partial   = (unsigned int*)(ws + 11173888);

    hipMemsetAsync(ws, 0, ZERO_SPAN, stream);

    k_outdeg_e0<<<G1, 1024, 0, stream>>>(src, dst, partial, bitmap, e0pack, e0cnt);
    k_auxred<<<260, 1024, 0, stream>>>(bitmap, loc, counters,
                                       partial, out_deg, wlin, wswz);
    k_e1_select<<<SELB, 1024, 0, stream>>>(src, dst, loc, bitmap,
                                           inF1, es_bucket);
    k_h0agg<<<F1CAP / 4, 256, 0, stream>>>(x, wswz, blin, es_bucket, out_deg,
                                           inF1, counters, agg1);
    k_h1<<<(F1CAP / 16) * 4, 256, 0, stream>>>(agg1, wc0, bc0, inF1,
                                               counters, h1);
    k_final<<<NAGENT, 1024, 0, stream>>>(e0pack, e0cnt, loc, out_deg, h1,
                                         wc1, bc1, wemb, bemb, out);
}

// Round 23
// 101.483 us; speedup vs baseline: 2.7541x; 2.7541x over previous
//
#include <hip/hip_runtime.h>
#include <hip/hip_bf16.h>

#define TOTAL_N   131072
#define NEDGE     4194304
#define NPG       2048
#define IN_DIM_K  128
#define HID_K     256
#define EMB_K     64
#define NAGENT    64

#define F1CAP     4096
#define APACK     128        // per-agent e0 slot cap
#define BCAP      96         // per-F1-node edge bucket cap (mean 32, P(>96)~1e-18)

#define G1        256                 // k1 histogram blocks (+256 pack blocks)
#define EPB1      (NEDGE / G1)        // 16384 edges per block
#define HWORDS    (TOTAL_N / 8)       // 16384 nibble-packed u32 words

#define SELB      256                 // k_e1_select blocks (persistent)
#define EPB       (NEDGE / SELB)      // 16384 edges per block

// ---------------- workspace layout (bytes) ----------------
// zeroed every launch [0, 34048):
//   0        counters  int[256]        ([1]=nF1)
//   1024     inF1      int[F1CAP]      16K
//   17408    e0cnt     int[64]         256B
//   17664    bitmap    u32[4096]       16K
// not zeroed (fully written before read):
//   65536    loc       int[TOTAL_N]    512K
//   589824   e0pack    int[64*APACK]   32K
//   622592   es_bucket int[F1CAP*BCAP] 1.5M
//   2195456  out_deg   u32[TOTAL_N]    512K
//   2719744  wswz      u16[32768]      64K
//   2785280  h1        f32[F1CAP*HID]  4M
//   6979584  agg1      f32[F1CAP*HID]  4M
//   11173888 partial   u32[G1*HWORDS]  16M
//   27951104 xb        u16[TOTAL_N*IN_DIM] 32M  (bf16-packed x, by k1 pack blocks)
// total ~61.5 MB

#define ZERO_SPAN 34048

typedef float f32x4 __attribute__((ext_vector_type(4)));
typedef short bf16x8 __attribute__((ext_vector_type(8)));

__device__ inline unsigned short f2bf(float f) {   // RNE f32->bf16
    unsigned int u = __float_as_uint(f);
    return (unsigned short)((u + 0x7FFFu + ((u >> 16) & 1u)) >> 16);
}

// K1 (heterogeneous, 512 blocks):
//   [0,256)   out-degree nibble histogram + e0 select + F1 bitmap marking
//   [256,512) stream-pack x (f32) -> xb (bf16)   — overlaps the latency-bound
//             histogram phase with pure-BW work
__global__ __launch_bounds__(1024) void k_outdeg_e0(
    const int* __restrict__ src, const int* __restrict__ dst,
    const float* __restrict__ x,
    unsigned int* __restrict__ partial,
    unsigned int* __restrict__ bitmap,
    int* __restrict__ e0pack, int* __restrict__ e0cnt,
    unsigned short* __restrict__ xb)
{
    __shared__ unsigned int hist[HWORDS];   // 64 KB (unused by pack blocks)
    int t = threadIdx.x;
    int b = blockIdx.x;

    if (b >= G1) {
        // ---- pack: 65536 floats per block, 16 float4 iters ----
        long long base = (long long)(b - G1) * 65536;
        const float4* xi = (const float4*)(x + base);
        ushort4* xo = (ushort4*)(xb + base);
        #pragma unroll 4
        for (int i = 0; i < 16; i++) {
            float4 v = xi[i * 1024 + t];
            ushort4 h;
            h.x = f2bf(v.x); h.y = f2bf(v.y); h.z = f2bf(v.z); h.w = f2bf(v.w);
            xo[i * 1024 + t] = h;
        }
        return;
    }

    #pragma unroll
    for (int i = 0; i < HWORDS / 1024; i++) hist[t + i * 1024] = 0u;
    __syncthreads();

    int ebase = b * EPB1;
    const int4* s4 = (const int4*)(src + ebase);
    const int4* d4 = (const int4*)(dst + ebase);
    #pragma unroll
    for (int i = 0; i < EPB1 / 4096; i++) {     // 4 iterations
        int4 sv = s4[i * 1024 + t];
        int4 dv = d4[i * 1024 + t];
        int ss[4] = {sv.x, sv.y, sv.z, sv.w};
        int dd[4] = {dv.x, dv.y, dv.z, dv.w};
        #pragma unroll
        for (int j = 0; j < 4; j++) {
            int s = ss[j], d = dd[j];
            atomicAdd(&hist[s >> 3], 1u << ((s & 7) * 4));
            if ((d & (NPG - 1)) == 0) {
                atomicOr(&bitmap[s >> 5], 1u << (s & 31));
                int a = d >> 11;
                int slot = atomicAdd(&e0cnt[a], 1);
                if (slot < APACK) e0pack[a * APACK + slot] = s;
            }
        }
    }
    __syncthreads();
    unsigned int* pout = partial + b * HWORDS;
    #pragma unroll
    for (int i = 0; i < HWORDS / 1024; i++) pout[t + i * 1024] = hist[t + i * 1024];
}

// K2 (merged aux+reduce, 260 blocks x 1024):
//   [0,128) compact | [128,256) out_deg reduce | [256,260) wprep
__global__ __launch_bounds__(1024) void k_auxred(
    const unsigned int* __restrict__ bitmap, int* __restrict__ loc,
    int* __restrict__ counters,
    const unsigned int* __restrict__ partial, unsigned int* __restrict__ out_deg,
    const float* __restrict__ wlin, unsigned short* __restrict__ wswz)
{
    int b = blockIdx.x;
    int t = threadIdx.x;
    if (b < 128) {
        __shared__ int cnt, gbase;
        if (t == 0) cnt = 0;
        __syncthreads();
        int v = b * 1024 + t;
        int f = (bitmap[v >> 5] >> (v & 31)) & 1u;
        int p = -1;
        if (f) p = atomicAdd(&cnt, 1);
        __syncthreads();
        if (t == 0) gbase = cnt ? atomicAdd(&counters[1], cnt) : 0;
        __syncthreads();
        int l = -1;
        if (p >= 0) { int id = gbase + p; if (id < F1CAP) l = id; }
        loc[v] = l;
    } else if (b < 256) {
        __shared__ unsigned int redE[8][128], redO[8][128];   // 8 KB
        int wl = t & 127, gs = t >> 7;
        int w = (b - 128) * 128 + wl;
        unsigned int accE = 0, accO = 0;
        #pragma unroll 8
        for (int i = 0; i < 32; i++) {
            unsigned int v = partial[(gs * 32 + i) * HWORDS + w];
            accE += v & 0x0F0F0F0Fu;
            accO += (v >> 4) & 0x0F0F0F0Fu;
        }
        redE[gs][wl] = accE;
        redO[gs][wl] = accO;
        __syncthreads();
        if (gs == 0) {
            unsigned int sE = 0, sO = 0;
            #pragma unroll
            for (int j = 0; j < 8; j++) { sE += redE[j][wl]; sO += redO[j][wl]; }
            uint4 lo = make_uint4(sE & 255u, sO & 255u, (sE >> 8) & 255u, (sO >> 8) & 255u);
            uint4 hi = make_uint4((sE >> 16) & 255u, (sO >> 16) & 255u, (sE >> 24) & 255u, (sO >> 24) & 255u);
            ((uint4*)(out_deg + 8 * w))[0] = lo;
            ((uint4*)(out_deg + 8 * w))[1] = hi;
        }
    } else {
        int g = (b - 256) * 1024 + t;            // 4096 items
        int lane = g & 63, ct = (g >> 6) & 15, kt = g >> 10;
        int colbase = ct * 16 + (lane & 15);
        int kbase = kt * 32 + (lane >> 4) * 8;
        unsigned short o[8];
        #pragma unroll
        for (int i = 0; i < 8; i++) o[i] = f2bf(wlin[(kbase + i) * HID_K + colbase]);
        *(ushort4*)(wswz + g * 8)     = make_ushort4(o[0], o[1], o[2], o[3]);
        *(ushort4*)(wswz + g * 8 + 4) = make_ushort4(o[4], o[5], o[6], o[7]);
    }
}

// K3: select edges with dst in F1 — direct bucket scatter; slot atomic doubles
// as the inF1 in-degree count.
__global__ __launch_bounds__(1024) void k_e1_select(
    const int* __restrict__ src, const int* __restrict__ dst,
    const int* __restrict__ loc, const unsigned int* __restrict__ bitmap,
    int* __restrict__ inF1, int* __restrict__ es_bucket)
{
    __shared__ unsigned int bm[TOTAL_N / 32];   // 16 KB
    int t = threadIdx.x;
    ((uint4*)bm)[t] = ((const uint4*)bitmap)[t];
    __syncthreads();

    int ebase = blockIdx.x * EPB;
    const int4* d4p = (const int4*)(dst + ebase);
    #pragma unroll
    for (int i = 0; i < EPB / 4096; i++) {      // 4 iterations
        int4 d4 = d4p[i * 1024 + t];
        int eidx = ebase + (i * 1024 + t) * 4;
        int dd[4] = {d4.x, d4.y, d4.z, d4.w};
        #pragma unroll
        for (int j = 0; j < 4; j++) {
            int d = dd[j];
            if ((bm[d >> 5] >> (d & 31)) & 1u) {
                int l = loc[d];
                if (l >= 0) {
                    int slot = atomicAdd(&inF1[l], 1);
                    if (slot < BCAP) es_bucket[l * BCAP + slot] = src[eidx + j];
                }
            }
        }
    }
}

// K4 (wave-per-node, zero-LDS): 4 nodes per block, one per 64-lane wave.
// A-fragments loaded DIRECTLY from bf16-packed xb (16 B/lane); row ids and
// norms distributed via __shfl. No barriers, no LDS, no per-edge conversion.
__global__ __launch_bounds__(256) void k_h0agg(
    const unsigned short* __restrict__ xb, const unsigned short* __restrict__ wswz,
    const float* __restrict__ blin, const int* __restrict__ es_bucket,
    const unsigned int* __restrict__ out_deg, const int* __restrict__ inF1,
    const int* __restrict__ counters, float* __restrict__ agg1)
{
    int nF1 = min(counters[1], F1CAP);
    int t = threadIdx.x;
    int w = t >> 6, lane = t & 63;
    int l = blockIdx.x * 4 + w;
    if (l >= nF1) return;                      // per-wave exit
    int cnt = min(inF1[l], BCAP);
    int ntile = (cnt + 31) >> 5;
    int cbase = lane & 15, rgrp = (lane >> 4) * 4;
    int ko = (lane >> 4) * 8;                  // k-offset inside 32-elem group

    float colacc[16];
    #pragma unroll
    for (int n = 0; n < 16; n++) colacc[n] = 0.f;

    const bf16x8 zf = {0, 0, 0, 0, 0, 0, 0, 0};

    for (int ti = 0; ti < ntile; ti++) {
        // lanes 0..31 fetch row ids + out-norms for this 32-row tile
        int s = -1; float e = 0.f;
        int r = ti * 32 + lane;
        if (lane < 32 && r < cnt) {
            s = es_bucket[l * BCAP + r];
            e = rsqrtf((float)max((int)out_deg[s], 1));
        }
        int s0 = __shfl(s, cbase);             // row (lane&15)   (m-tile 0)
        int s1 = __shfl(s, 16 + cbase);        // row 16+(lane&15)(m-tile 1)
        float e0[4], e1[4];
        #pragma unroll
        for (int j = 0; j < 4; j++) {
            e0[j] = __shfl(e, rgrp + j);
            e1[j] = __shfl(e, 16 + rgrp + j);
        }

        // A-fragments straight from global bf16 rows
        bf16x8 a0[4], a1[4];
        const unsigned short* x0 = xb + (long long)s0 * IN_DIM_K;
        const unsigned short* x1 = xb + (long long)s1 * IN_DIM_K;
        #pragma unroll
        for (int kt = 0; kt < 4; kt++) {
            a0[kt] = (s0 >= 0) ? *(const bf16x8*)(x0 + kt * 32 + ko) : zf;
            a1[kt] = (s1 >= 0) ? *(const bf16x8*)(x1 + kt * 32 + ko) : zf;
        }

        #pragma unroll
        for (int n = 0; n < 16; n++) {
            f32x4 acc0 = (f32x4){0.f, 0.f, 0.f, 0.f};
            f32x4 acc1 = (f32x4){0.f, 0.f, 0.f, 0.f};
            #pragma unroll
            for (int kt = 0; kt < 4; kt++) {
                bf16x8 bf = *(const bf16x8*)(wswz + ((kt * 16 + n) * 64 + lane) * 8);
                acc0 = __builtin_amdgcn_mfma_f32_16x16x32_bf16(a0[kt], bf, acc0, 0, 0, 0);
                acc1 = __builtin_amdgcn_mfma_f32_16x16x32_bf16(a1[kt], bf, acc1, 0, 0, 0);
            }
            float bj = blin[n * 16 + cbase];
            float part = 0.f;
            #pragma unroll
            for (int j = 0; j < 4; j++) {
                part += fmaxf(acc0[j] + bj, 0.f) * e0[j];
                part += fmaxf(acc1[j] + bj, 0.f) * e1[j];
            }
            part += __shfl_xor(part, 16);
            part += __shfl_xor(part, 32);
            colacc[n] += part;
        }
    }

    if (lane < 16) {
        #pragma unroll
        for (int n = 0; n < 16; n++)
            agg1[(long long)l * HID_K + n * 16 + lane] = colacc[n];
    }
}

// K5: h1 = relu((agg1*in_norm)@wc0 + bc0), column-split 4x (r18-proven)
__global__ __launch_bounds__(256) void k_h1(
    const float* __restrict__ agg1, const float* __restrict__ wc0,
    const float* __restrict__ bc0,
    const int* __restrict__ inF1,
    const int* __restrict__ counters, float* __restrict__ h1)
{
    __shared__ float as[16][HID_K];   // 16 KB
    __shared__ float ns[16];

    int nF1 = min(counters[1], F1CAP);
    int rt = blockIdx.x >> 2;
    int cq = blockIdx.x & 3;
    int base = rt * 16;
    if (base >= nF1) return;
    int t = threadIdx.x;

    if (t < 16) {
        int l = base + t;
        ns[t] = (l < nF1) ? rsqrtf((float)max(inF1[l], 1)) : 0.f;
    }
    __syncthreads();

    #pragma unroll
    for (int i = 0; i < 4; i++) {
        int idx = t + i * 256;
        int e = idx >> 6;
        int q = idx & 63;
        int l = base + e;
        float4 v = make_float4(0.f, 0.f, 0.f, 0.f);
        if (l < nF1) v = ((const float4*)(agg1 + (long long)l * HID_K))[q];
        float sc = ns[e];
        v.x *= sc; v.y *= sc; v.z *= sc; v.w *= sc;
        ((float4*)as[e])[q] = v;
    }
    __syncthreads();

    int j = cq * 64 + (t & 63);
    int rg = (t >> 6) * 4;
    float acc[4] = {0.f, 0.f, 0.f, 0.f};

    for (int k = 0; k < HID_K; k += 4) {
        float w0 = wc0[(k + 0) * HID_K + j];
        float w1 = wc0[(k + 1) * HID_K + j];
        float w2 = wc0[(k + 2) * HID_K + j];
        float w3 = wc0[(k + 3) * HID_K + j];
        #pragma unroll
        for (int e = 0; e < 4; e++) {
            float4 av = *(const float4*)&as[rg + e][k];
            acc[e] = fmaf(av.x, w0, acc[e]);
            acc[e] = fmaf(av.y, w1, acc[e]);
            acc[e] = fmaf(av.z, w2, acc[e]);
            acc[e] = fmaf(av.w, w3, acc[e]);
        }
    }

    float bj = bc0[j];
    #pragma unroll
    for (int e = 0; e < 4; e++) {
        int l = base + rg + e;
        if (l < nF1) h1[(long long)l * HID_K + j] = fmaxf(acc[e] + bj, 0.f);
    }
}

// K6 (widened, r19-proven): per agent, 1024 threads; phase-sliced GEMVs.
__global__ __launch_bounds__(1024) void k_final(
    const int* __restrict__ e0pack, const int* __restrict__ e0cnt,
    const int* __restrict__ loc, const unsigned int* __restrict__ out_deg,
    const float* __restrict__ h1,
    const float* __restrict__ wc1, const float* __restrict__ bc1,
    const float* __restrict__ wemb, const float* __restrict__ bemb,
    float* __restrict__ out)
{
    __shared__ float part4[4][HID_K];
    __shared__ float a_s[HID_K];
    __shared__ float h2[HID_K];
    __shared__ float o_part[16][EMB_K];
    __shared__ int   ls[APACK];
    __shared__ float scs[APACK];
    int a = blockIdx.x;
    int t = threadIdx.x;

    int n0 = e0cnt[a];
    int ne = min(n0, APACK);
    if (t < ne) {
        int s = e0pack[a * APACK + t];
        int l = loc[s];
        ls[t] = l;
        scs[t] = (l >= 0) ? rsqrtf((float)max((int)out_deg[s], 1)) : 0.f;
    }
    __syncthreads();

    {
        int col = t & 255, sl = t >> 8;
        float acc = 0.f;
        for (int i = sl; i < ne; i += 4) {
            int l = ls[i];
            if (l >= 0) acc = fmaf(scs[i], h1[(long long)l * HID_K + col], acc);
        }
        part4[sl][col] = acc;
    }
    __syncthreads();
    if (t < HID_K) {
        float s = part4[0][t] + part4[1][t] + part4[2][t] + part4[3][t];
        a_s[t] = s * rsqrtf((float)max(n0, 1));
    }
    __syncthreads();

    {
        int col = t & 255, sl = t >> 8;
        float acc = 0.f;
        int k0 = sl * 64;
        for (int k = k0; k < k0 + 64; k++)
            acc = fmaf(a_s[k], wc1[k * HID_K + col], acc);
        part4[sl][col] = acc;
    }
    __syncthreads();
    if (t < HID_K) {
        float s = part4[0][t] + part4[1][t] + part4[2][t] + part4[3][t];
        h2[t] = fmaxf(s + bc1[t], 0.f);
    }
    __syncthreads();

    {
        int col = t & 63, sl = t >> 6;
        float acc = 0.f;
        int k0 = sl * 16;
        for (int k = k0; k < k0 + 16; k++)
            acc = fmaf(h2[k], wemb[k * EMB_K + col], acc);
        o_part[sl][col] = acc;
    }
    __syncthreads();
    if (t < EMB_K) {
        float o = bemb[t];
        #pragma unroll
        for (int s = 0; s < 16; s++) o += o_part[s][t];
        out[a * EMB_K + t] = o;
    }
}

extern "C" void kernel_launch(void* const* d_in, const int* in_sizes, int n_in,
                              void* d_out, int out_size, void* d_ws, size_t ws_size,
                              hipStream_t stream)
{
    const float* x    = (const float*)d_in[0];
    const int*   src  = (const int*)d_in[1];
    const int*   dst  = (const int*)d_in[2];
    const float* wlin = (const float*)d_in[5];
    const float* blin = (const float*)d_in[6];
    const float* wc0  = (const float*)d_in[7];
    const float* bc0  = (const float*)d_in[8];
    const float* wc1  = (const float*)d_in[9];
    const float* bc1  = (const float*)d_in[10];
    const float* wemb = (const float*)d_in[11];
    const float* bemb = (const float*)d_in[12];
    float* out = (float*)d_out;

    char* ws = (char*)d_ws;
    int*            counters  = (int*)(ws + 0);
    int*            inF1      = (int*)(ws + 1024);
    int*            e0cnt     = (int*)(ws + 17408);
    unsigned int*   bitmap    = (unsigned int*)(ws + 17664);
    int*            loc       = (int*)(ws + 65536);
    int*            e0pack    = (int*)(ws + 589824);
    int*            es_bucket = (int*)(ws + 622592);
    unsigned int*   out_deg   = (unsigned int*)(ws + 2195456);
    unsigned short* wswz      = (unsigned short*)(ws + 2719744);
    float*          h1        = (float*)(ws + 2785280);
    float*          agg1      = (float*)(ws + 6979584);
    unsigned int*   partial   = (unsigned int*)(ws + 11173888);
    unsigned short* xb        = (unsigned short*)(ws + 27951104);

    hipMemsetAsync(ws, 0, ZERO_SPAN, stream);

    k_outdeg_e0<<<G1 + 256, 1024, 0, stream>>>(src, dst, x, partial, bitmap,
                                               e0pack, e0cnt, xb);
    k_auxred<<<260, 1024, 0, stream>>>(bitmap, loc, counters,
                                       partial, out_deg, wlin, wswz);
    k_e1_select<<<SELB, 1024, 0, stream>>>(src, dst, loc, bitmap,
                                           inF1, es_bucket);
    k_h0agg<<<F1CAP / 4, 256, 0, stream>>>(xb, wswz, blin, es_bucket, out_deg,
                                           inF1, counters, agg1);
    k_h1<<<(F1CAP / 16) * 4, 256, 0, stream>>>(agg1, wc0, bc0, inF1,
                                               counters, h1);
    k_final<<<NAGENT, 1024, 0, stream>>>(e0pack, e0cnt, loc, out_deg, h1,
                                         wc1, bc1, wemb, bemb, out);
}